// Round 7
// baseline (33.426 us; speedup 1.0000x reference)
//
#include <hip/hip_runtime.h>

// MaxRecallLoss: ONE fused kernel. 2047 worker blocks + 1 finisher block
// (= 2048 = exact machine fill at 4 waves/block), 64 distributed completion
// counters. B = 2,097,152, C = 8, cancer classes {0,1,3} -> mask 0xB.
//
// R2 lesson:  per-block __threadfence (buffer_wbl2) -> 4x regression.
// R5 lesson:  single-line counter -> 2048 serialized cross-XCD RMWs ~27us.
// Fix: relaxed agent-scope atomics (coherent point, no wbl2) + vmcnt(0)
// release ordering (validated correct in R5) + 64 counter lines (~32 RMWs
// each, drained in parallel) + polling finisher instead of a 2nd dispatch.
//
// d_ws: part[3*NBW] floats at offset 0 | ctr[64] uints at byte 24576.

constexpr int C    = 8;
constexpr int NT   = 256;    // threads per block (4 waves)
constexpr int NBW  = 2047;   // worker blocks; +1 finisher = 2048 total
constexpr int NCTR = 64;     // distributed completion counters

__device__ __forceinline__ float wave_bfly_sum(float v) {
    #pragma unroll
    for (int off = 1; off < 64; off <<= 1) v += __shfl_xor(v, off, 64);
    return v;
}
__device__ __forceinline__ unsigned wave_bfly_sum_u(unsigned v) {
    #pragma unroll
    for (int off = 1; off < 64; off <<= 1) v += __shfl_xor(v, off, 64);
    return v;
}

__device__ __forceinline__ void row_loss(const float l[8], int t, float bw,
                                         float& ce_sum, float& tp_sum,
                                         float& cnt_sum) {
    const float inv_temp = 1.0f / 1.5f;
    const float c_uni   = 0.05f / 8.0f;
    const float c_one   = 1.0f - 0.05f;
    const float b_uni   = 0.1f / 8.0f;
    const float b_one   = 1.0f - 0.1f;
    const float b_extra = 0.1f * 0.5f / 3.0f;
    const float b_norm  = 1.0f / (1.0f + 3.0f * (0.1f * 0.5f / 3.0f)); // 1/1.05

    // max + argmax (first-max tie-break, matches jnp.argmax)
    float m = l[0];
    int   p = 0;
    #pragma unroll
    for (int j = 1; j < 8; ++j) { if (l[j] > m) { m = l[j]; p = j; } }

    // temp-1 softmax pieces (cancer prob)
    float se = 0.0f, e0, e1, e3;
    {
        float e[8];
        #pragma unroll
        for (int j = 0; j < 8; ++j) { e[j] = __expf(l[j] - m); se += e[j]; }
        e0 = e[0]; e1 = e[1]; e3 = e[3];
    }
    const float cp = (e0 + e1 + e3) / se;

    // temp-1.5 log-sum-exp
    float se2 = 0.0f;
    #pragma unroll
    for (int j = 0; j < 8; ++j) se2 += __expf((l[j] - m) * inv_temp);
    const float logZ = m * inv_temp + __logf(se2);

    // dot(smoothed_labels, x) without materializing the row
    float S = 0.0f;
    #pragma unroll
    for (int j = 0; j < 8; ++j) S += l[j];
    const float X  = S * inv_temp;
    const float Xc = (l[0] + l[1] + l[3]) * inv_temp;
    float lt = l[0];
    #pragma unroll
    for (int j = 1; j < 8; ++j) lt = (t == j) ? l[j] : lt;
    const float xt = lt * inv_temp;

    const bool isct = ((1u << t) & 0xBu) != 0u;
    const bool iscp = ((1u << p) & 0xBu) != 0u;

    float dot;
    if (isct) dot = c_uni * X + c_one * xt;
    else      dot = (b_uni * X + b_one * xt + b_extra * Xc) * b_norm;

    float ce = (logZ - dot) * bw;

    float mult = (isct && !iscp) ? 3.0f : 1.0f;
    if (t == 0 && !iscp) mult = 5.0f;
    if (isct && p != t) mult *= 2.0f;
    ce *= mult;

    ce_sum += ce;
    if (isct) { tp_sum += cp; cnt_sum += 1.0f; }
}

__global__ __launch_bounds__(NT) void mrl_fused(
    const float* __restrict__ logits,
    const int*   __restrict__ targets,
    const float* __restrict__ counts,
    float*        part,   // [3*NBW]
    unsigned int* ctr,    // [NCTR], memset to 0 per call
    float*        out,
    int B)
{
    __shared__ float s_red[(NT / 64) * 3];
    const int bid  = blockIdx.x;
    const int lane = threadIdx.x & 63;
    const int wid  = threadIdx.x >> 6;

    if (bid != NBW) {
        // ---------------- worker ----------------
        float w[C];
        float ws = 0.0f;
        #pragma unroll
        for (int c = 0; c < C; ++c) { w[c] = rsqrtf(counts[c] + 1.0f); ws += w[c]; }
        const float scale = (float)C / ws;

        float ce_sum = 0.0f, tp_sum = 0.0f, cnt_sum = 0.0f;

        const int NQ   = B >> 2;        // row-quads: 524288
        const int nthr = NBW * NT;      // 524032 worker threads
        for (int q = bid * NT + threadIdx.x; q < NQ; q += nthr) {
            const long base = (long)q * 4;
            const float4* rowp = reinterpret_cast<const float4*>(logits + base * 8);
            float4 r[8];
            #pragma unroll
            for (int k = 0; k < 8; ++k) r[k] = rowp[k];
            const int4 t4 = *reinterpret_cast<const int4*>(targets + base);
            const int ts[4] = {t4.x, t4.y, t4.z, t4.w};

            #pragma unroll
            for (int j = 0; j < 4; ++j) {
                const int t = ts[j];
                float bw = w[0];
                #pragma unroll
                for (int c = 1; c < C; ++c) bw = (t == c) ? w[c] : bw;
                bw *= scale;
                const float l[8] = {r[2*j].x,   r[2*j].y,   r[2*j].z,   r[2*j].w,
                                    r[2*j+1].x, r[2*j+1].y, r[2*j+1].z, r[2*j+1].w};
                row_loss(l, t, bw, ce_sum, tp_sum, cnt_sum);
            }
        }

        // block reduce (fixed order -> deterministic)
        float v0 = wave_bfly_sum(ce_sum);
        float v1 = wave_bfly_sum(tp_sum);
        float v2 = wave_bfly_sum(cnt_sum);
        if (lane == 0) {
            s_red[wid * 3 + 0] = v0;
            s_red[wid * 3 + 1] = v1;
            s_red[wid * 3 + 2] = v2;
        }
        __syncthreads();
        if (threadIdx.x == 0) {
            float r0 = 0.0f, r1 = 0.0f, r2 = 0.0f;
            #pragma unroll
            for (int w2 = 0; w2 < NT / 64; ++w2) {
                r0 += s_red[w2 * 3 + 0];
                r1 += s_red[w2 * 3 + 1];
                r2 += s_red[w2 * 3 + 2];
            }
            // coherent relaxed stores (no L2 dirtying, no wbl2)
            __hip_atomic_store(&part[bid],           r0, __ATOMIC_RELAXED, __HIP_MEMORY_SCOPE_AGENT);
            __hip_atomic_store(&part[NBW + bid],     r1, __ATOMIC_RELAXED, __HIP_MEMORY_SCOPE_AGENT);
            __hip_atomic_store(&part[2 * NBW + bid], r2, __ATOMIC_RELAXED, __HIP_MEMORY_SCOPE_AGENT);
            // order partial stores before the completion increment (wave-local)
            asm volatile("s_waitcnt vmcnt(0)" ::: "memory");
            __hip_atomic_fetch_add(&ctr[bid & (NCTR - 1)], 1u,
                                   __ATOMIC_RELAXED, __HIP_MEMORY_SCOPE_AGENT);
        }
    } else {
        // ---------------- finisher ----------------
        if (wid == 0) {
            for (;;) {
                unsigned v = (lane < NCTR)
                    ? __hip_atomic_load(&ctr[lane], __ATOMIC_RELAXED, __HIP_MEMORY_SCOPE_AGENT)
                    : 0u;
                if (wave_bfly_sum_u(v) == (unsigned)NBW) break;
                __builtin_amdgcn_s_sleep(8);
            }
        }
        __syncthreads();   // all 4 waves wait for completion signal

        float ce = 0.0f, tp = 0.0f, cnt = 0.0f;
        for (int k = threadIdx.x; k < NBW; k += NT) {
            ce  += __hip_atomic_load(&part[k],           __ATOMIC_RELAXED, __HIP_MEMORY_SCOPE_AGENT);
            tp  += __hip_atomic_load(&part[NBW + k],     __ATOMIC_RELAXED, __HIP_MEMORY_SCOPE_AGENT);
            cnt += __hip_atomic_load(&part[2 * NBW + k], __ATOMIC_RELAXED, __HIP_MEMORY_SCOPE_AGENT);
        }
        float v0 = wave_bfly_sum(ce);
        float v1 = wave_bfly_sum(tp);
        float v2 = wave_bfly_sum(cnt);
        if (lane == 0) {
            s_red[wid * 3 + 0] = v0;
            s_red[wid * 3 + 1] = v1;
            s_red[wid * 3 + 2] = v2;
        }
        __syncthreads();
        if (threadIdx.x == 0) {
            float r0 = 0.0f, r1 = 0.0f, r2 = 0.0f;
            #pragma unroll
            for (int w2 = 0; w2 < NT / 64; ++w2) {
                r0 += s_red[w2 * 3 + 0];
                r1 += s_red[w2 * 3 + 1];
                r2 += s_red[w2 * 3 + 2];
            }
            const float base_loss   = r0 / (float)B;
            const float recall_loss = 1.0f - r1 / (r2 + 1e-8f);
            out[0] = base_loss + 0.5f * recall_loss;
        }
    }
}

extern "C" void kernel_launch(void* const* d_in, const int* in_sizes, int n_in,
                              void* d_out, int out_size, void* d_ws, size_t ws_size,
                              hipStream_t stream) {
    const float* logits  = (const float*)d_in[0];
    const int*   targets = (const int*)d_in[1];
    const float* counts  = (const float*)d_in[2];
    float* out  = (float*)d_out;
    float* part = (float*)d_ws;                                   // 3*NBW floats
    unsigned int* ctr = (unsigned int*)((char*)d_ws + 24576);     // 64 uints

    const int B = in_sizes[1];

    hipMemsetAsync(ctr, 0, NCTR * sizeof(unsigned int), stream);
    mrl_fused<<<NBW + 1, NT, 0, stream>>>(logits, targets, counts, part, ctr, out, B);
}

// Round 8
// 24.777 us; speedup vs baseline: 1.3490x; 1.3490x over previous
//
#include <hip/hip_runtime.h>

// MaxRecallLoss: two-kernel structure (R2/R5/R7: any fused cross-workgroup
// completion protocol costs >=10us extra on 8-XCD gfx950 -> closed).
// pass1 = exact-cover streamer (4 rows/thread), lean-VALU per-row math:
//   - argmax replaced by {max-of-cancer, max-of-benign} comparison
//   - cp division replaced by v_rcp_f32
//   - shared (l-m) feeding both exp families via exp2
// pass2 = tiny deterministic final reduce.
// Cancer classes {0,1,3} -> mask 0xB.

constexpr int C   = 8;
constexpr int NT  = 256;   // threads per block
constexpr int NB  = 2048;  // NB*NT*RPT == 2^21 == B exactly
constexpr int RPT = 4;     // rows per thread

__device__ __forceinline__ float wave_reduce_sum(float v) {
    #pragma unroll
    for (int off = 32; off > 0; off >>= 1) v += __shfl_down(v, off, 64);
    return v;
}

__device__ __forceinline__ void row_loss(const float l[8], int t, float bw,
                                         float& ce_sum, float& tp_sum,
                                         float& cnt_sum) {
    const float L2E = 1.4426950408889634f;   // log2(e)
    const float K23 = 0.9617966939259756f;   // log2(e) * 2/3
    const float inv_temp = 2.0f / 3.0f;
    const float c_uni   = 0.05f / 8.0f;
    const float c_one   = 1.0f - 0.05f;
    const float b_uni   = 0.1f / 8.0f;
    const float b_one   = 1.0f - 0.1f;
    const float b_extra = 0.1f * 0.5f / 3.0f;
    const float b_norm  = 1.0f / 1.05f;

    // max over cancer {0,1,3} and benign {2,4,5,6,7} sets.
    // iscp (pred is cancer) == mc > mb; pred==t == (l[t]==m).
    // (exact float ties between classes: measure-zero for seeded normals)
    const float mc = fmaxf(fmaxf(l[0], l[1]), l[3]);
    const float mb = fmaxf(fmaxf(fmaxf(l[2], l[4]), fmaxf(l[5], l[6])), l[7]);
    const float m  = fmaxf(mc, mb);
    const bool iscp = mc > mb;

    // both exp families from shared (l - m)
    float ev[8];
    float se = 0.0f, se2 = 0.0f;
    #pragma unroll
    for (int j = 0; j < 8; ++j) {
        const float d = l[j] - m;
        const float e1 = exp2f(d * L2E);   // temp-1 softmax term
        const float e2 = exp2f(d * K23);   // temp-1.5 term
        ev[j] = e1;
        se  += e1;
        se2 += e2;
    }
    const float cp = (ev[0] + ev[1] + ev[3]) * __builtin_amdgcn_rcpf(se);

    const float logZ = m * inv_temp + __logf(se2);

    // dot(smoothed_labels, x)
    float S = 0.0f;
    #pragma unroll
    for (int j = 0; j < 8; ++j) S += l[j];
    const float X  = S * inv_temp;
    const float Xc = (l[0] + l[1] + l[3]) * inv_temp;
    float lt = l[0];
    #pragma unroll
    for (int j = 1; j < 8; ++j) lt = (t == j) ? l[j] : lt;
    const float xt = lt * inv_temp;

    const bool isct = ((1u << t) & 0xBu) != 0u;

    const float dot = isct ? (c_uni * X + c_one * xt)
                           : (b_uni * X + b_one * xt + b_extra * Xc) * b_norm;

    float mult = (isct && !iscp) ? 3.0f : 1.0f;
    if (t == 0 && !iscp) mult = 5.0f;
    if (isct && (lt != m)) mult *= 2.0f;   // hard mining: pred != target

    ce_sum += (logZ - dot) * bw * mult;
    if (isct) { tp_sum += cp; cnt_sum += 1.0f; }
}

__global__ __launch_bounds__(NT) void mrl_pass1(
    const float* __restrict__ logits,
    const int*   __restrict__ targets,
    const float* __restrict__ counts,
    float*       __restrict__ part,   // [3*NB]: ce | tp | cnt
    int B)
{
    __shared__ float s_bw[C];
    __shared__ float s_red[(NT / 64) * 3];

    if (threadIdx.x == 0) {
        float w[C];
        float ws = 0.0f;
        #pragma unroll
        for (int c = 0; c < C; ++c) { w[c] = rsqrtf(counts[c] + 1.0f); ws += w[c]; }
        const float scale = (float)C / ws;
        #pragma unroll
        for (int c = 0; c < C; ++c) s_bw[c] = w[c] * scale;
    }
    __syncthreads();

    float ce_sum = 0.0f, tp_sum = 0.0f, cnt_sum = 0.0f;

    const long tid  = (long)blockIdx.x * NT + threadIdx.x;
    const long base = tid * RPT;

    if (base + RPT <= B) {
        // fast path (always for B = 2^21): issue ALL loads up front
        const float4* rowp = reinterpret_cast<const float4*>(logits + base * 8);
        float4 r[2 * RPT];
        #pragma unroll
        for (int q = 0; q < 2 * RPT; ++q) r[q] = rowp[q];
        const int4 t4 = *reinterpret_cast<const int4*>(targets + base);
        const int ts[RPT] = {t4.x, t4.y, t4.z, t4.w};

        #pragma unroll
        for (int j = 0; j < RPT; ++j) {
            const float l[8] = {r[2*j].x,   r[2*j].y,   r[2*j].z,   r[2*j].w,
                                r[2*j+1].x, r[2*j+1].y, r[2*j+1].z, r[2*j+1].w};
            row_loss(l, ts[j], s_bw[ts[j]], ce_sum, tp_sum, cnt_sum);
        }
    } else {
        // generic tail (unused when B divides evenly)
        for (long i = base; i < B; ++i) {
            const float4* row = reinterpret_cast<const float4*>(logits + i * 8);
            const float4 a = row[0];
            const float4 b = row[1];
            const float l[8] = {a.x, a.y, a.z, a.w, b.x, b.y, b.z, b.w};
            const int t = targets[i];
            row_loss(l, t, s_bw[t], ce_sum, tp_sum, cnt_sum);
        }
    }

    // block reduction (fixed order -> deterministic)
    float v0 = wave_reduce_sum(ce_sum);
    float v1 = wave_reduce_sum(tp_sum);
    float v2 = wave_reduce_sum(cnt_sum);
    const int lane = threadIdx.x & 63;
    const int wid  = threadIdx.x >> 6;
    if (lane == 0) {
        s_red[wid * 3 + 0] = v0;
        s_red[wid * 3 + 1] = v1;
        s_red[wid * 3 + 2] = v2;
    }
    __syncthreads();
    if (threadIdx.x == 0) {
        float r0 = 0.0f, r1 = 0.0f, r2 = 0.0f;
        #pragma unroll
        for (int w = 0; w < NT / 64; ++w) {
            r0 += s_red[w * 3 + 0];
            r1 += s_red[w * 3 + 1];
            r2 += s_red[w * 3 + 2];
        }
        part[blockIdx.x]          = r0;
        part[NB + blockIdx.x]     = r1;
        part[2 * NB + blockIdx.x] = r2;
    }
}

__global__ __launch_bounds__(NT) void mrl_pass2(
    const float* __restrict__ part,
    float*       __restrict__ out,
    int B)
{
    __shared__ float s_red[(NT / 64) * 3];

    // NB=2048 floats per segment = 512 float4 = 2 float4 per thread
    const float4* p4 = reinterpret_cast<const float4*>(part);
    const int k = threadIdx.x;
    float ce, tp, cnt;
    {
        const float4 a1 = p4[k];
        const float4 a2 = p4[k + NT];
        const float4 b1 = p4[NB / 4 + k];
        const float4 b2 = p4[NB / 4 + k + NT];
        const float4 c1 = p4[2 * (NB / 4) + k];
        const float4 c2 = p4[2 * (NB / 4) + k + NT];
        ce  = ((a1.x + a1.y) + (a1.z + a1.w)) + ((a2.x + a2.y) + (a2.z + a2.w));
        tp  = ((b1.x + b1.y) + (b1.z + b1.w)) + ((b2.x + b2.y) + (b2.z + b2.w));
        cnt = ((c1.x + c1.y) + (c1.z + c1.w)) + ((c2.x + c2.y) + (c2.z + c2.w));
    }
    float v0 = wave_reduce_sum(ce);
    float v1 = wave_reduce_sum(tp);
    float v2 = wave_reduce_sum(cnt);
    const int lane = threadIdx.x & 63;
    const int wid  = threadIdx.x >> 6;
    if (lane == 0) {
        s_red[wid * 3 + 0] = v0;
        s_red[wid * 3 + 1] = v1;
        s_red[wid * 3 + 2] = v2;
    }
    __syncthreads();
    if (threadIdx.x == 0) {
        float r0 = 0.0f, r1 = 0.0f, r2 = 0.0f;
        #pragma unroll
        for (int w = 0; w < NT / 64; ++w) {
            r0 += s_red[w * 3 + 0];
            r1 += s_red[w * 3 + 1];
            r2 += s_red[w * 3 + 2];
        }
        const float base_loss   = r0 / (float)B;
        const float recall_loss = 1.0f - r1 / (r2 + 1e-8f);
        out[0] = base_loss + 0.5f * recall_loss;
    }
}

extern "C" void kernel_launch(void* const* d_in, const int* in_sizes, int n_in,
                              void* d_out, int out_size, void* d_ws, size_t ws_size,
                              hipStream_t stream) {
    const float* logits  = (const float*)d_in[0];
    const int*   targets = (const int*)d_in[1];
    const float* counts  = (const float*)d_in[2];
    float* out  = (float*)d_out;
    float* part = (float*)d_ws;   // 3*NB floats = 24 KB scratch
    const int B = in_sizes[1];

    mrl_pass1<<<NB, NT, 0, stream>>>(logits, targets, counts, part, B);
    mrl_pass2<<<1, NT, 0, stream>>>(part, out, B);
}

// Round 9
// 21.823 us; speedup vs baseline: 1.5316x; 1.1354x over previous
//
#include <hip/hip_runtime.h>

// MaxRecallLoss: R3's proven-best pass1 (22.08us) + single-wave barrier-free
// pass2. Cancer classes {0,1,3} -> mask 0xB.
//
// Closed paths (measured): fused last-block-done w/ threadfence (R2: +63us),
// w/ relaxed agent atomics single counter (R5: +22us), w/ 64 distributed
// counters + polling finisher (R7: +11us). VALU trimming (R8): no effect.
// Max-ILP loop-free layout (R4): no effect vs grid-stride.

constexpr int C  = 8;
constexpr int NT = 256;   // pass1 threads per block
constexpr int NB = 1024;  // pass1 blocks (4 per CU), grid-stride over B

__device__ __forceinline__ float wave_reduce_sum(float v) {
    #pragma unroll
    for (int off = 32; off > 0; off >>= 1) v += __shfl_down(v, off, 64);
    return v;
}

__global__ __launch_bounds__(NT) void mrl_pass1(
    const float* __restrict__ logits,
    const int*   __restrict__ targets,
    const float* __restrict__ counts,
    float*       __restrict__ part,   // [3*NB]: ce | tp | cnt
    int B)
{
    __shared__ float s_bw[C];
    __shared__ float s_red[(NT / 64) * 3];

    if (threadIdx.x == 0) {
        float w[C];
        float ws = 0.0f;
        #pragma unroll
        for (int c = 0; c < C; ++c) { w[c] = rsqrtf(counts[c] + 1.0f); ws += w[c]; }
        const float scale = (float)C / ws;
        #pragma unroll
        for (int c = 0; c < C; ++c) s_bw[c] = w[c] * scale;
    }
    __syncthreads();

    const float inv_temp = 1.0f / 1.5f;
    const float c_uni   = 0.05f / 8.0f;
    const float c_one   = 1.0f - 0.05f;
    const float b_uni   = 0.1f / 8.0f;
    const float b_one   = 1.0f - 0.1f;
    const float b_extra = 0.1f * 0.5f / 3.0f;
    const float b_norm  = 1.0f / (1.0f + 3.0f * (0.1f * 0.5f / 3.0f)); // 1/1.05

    float ce_sum = 0.0f, tp_sum = 0.0f, cnt_sum = 0.0f;

    const int stride = gridDim.x * blockDim.x;
    #pragma unroll 2
    for (int i = blockIdx.x * blockDim.x + threadIdx.x; i < B; i += stride) {
        const float4* row = reinterpret_cast<const float4*>(logits + (size_t)i * 8);
        const float4 a = row[0];
        const float4 b = row[1];
        const float l[8] = {a.x, a.y, a.z, a.w, b.x, b.y, b.z, b.w};
        const int t = targets[i];

        // max + argmax (first-max tie-break, matches jnp.argmax)
        float m = l[0];
        int   p = 0;
        #pragma unroll
        for (int j = 1; j < 8; ++j) { if (l[j] > m) { m = l[j]; p = j; } }

        // temp-1 softmax pieces (cancer prob)
        float se = 0.0f, e0, e1, e3;
        {
            float e[8];
            #pragma unroll
            for (int j = 0; j < 8; ++j) { e[j] = __expf(l[j] - m); se += e[j]; }
            e0 = e[0]; e1 = e[1]; e3 = e[3];
        }
        const float cp = (e0 + e1 + e3) / se;

        // temp-1.5 log-sum-exp
        float se2 = 0.0f;
        #pragma unroll
        for (int j = 0; j < 8; ++j) se2 += __expf((l[j] - m) * inv_temp);
        const float logZ = m * inv_temp + __logf(se2);

        // dot(smoothed_labels, x) without materializing the row
        float S = 0.0f;
        #pragma unroll
        for (int j = 0; j < 8; ++j) S += l[j];
        const float X  = S * inv_temp;
        const float Xc = (l[0] + l[1] + l[3]) * inv_temp;
        float lt = l[0];
        #pragma unroll
        for (int j = 1; j < 8; ++j) lt = (t == j) ? l[j] : lt;
        const float xt = lt * inv_temp;

        const bool isct = ((1u << t) & 0xBu) != 0u;
        const bool iscp = ((1u << p) & 0xBu) != 0u;

        float dot;
        if (isct) dot = c_uni * X + c_one * xt;
        else      dot = (b_uni * X + b_one * xt + b_extra * Xc) * b_norm;

        float ce = (logZ - dot) * s_bw[t];

        float mult = (isct && !iscp) ? 3.0f : 1.0f;
        if (t == 0 && !iscp) mult = 5.0f;
        if (isct && p != t) mult *= 2.0f;
        ce *= mult;

        ce_sum += ce;
        if (isct) { tp_sum += cp; cnt_sum += 1.0f; }
    }

    // block reduction (fixed order -> deterministic)
    float v0 = wave_reduce_sum(ce_sum);
    float v1 = wave_reduce_sum(tp_sum);
    float v2 = wave_reduce_sum(cnt_sum);
    const int lane = threadIdx.x & 63;
    const int wid  = threadIdx.x >> 6;
    if (lane == 0) {
        s_red[wid * 3 + 0] = v0;
        s_red[wid * 3 + 1] = v1;
        s_red[wid * 3 + 2] = v2;
    }
    __syncthreads();
    if (threadIdx.x == 0) {
        float r0 = 0.0f, r1 = 0.0f, r2 = 0.0f;
        #pragma unroll
        for (int w = 0; w < NT / 64; ++w) {
            r0 += s_red[w * 3 + 0];
            r1 += s_red[w * 3 + 1];
            r2 += s_red[w * 3 + 2];
        }
        part[blockIdx.x]          = r0;
        part[NB + blockIdx.x]     = r1;
        part[2 * NB + blockIdx.x] = r2;
    }
}

// Single-wave, LDS-free, barrier-free final reduce.
// NB=1024 floats per segment = 256 float4 = 4 float4 per lane.
__global__ __launch_bounds__(64) void mrl_pass2(
    const float* __restrict__ part,
    float*       __restrict__ out,
    int B)
{
    const float4* p4 = reinterpret_cast<const float4*>(part);
    const int lane = threadIdx.x;           // 0..63
    constexpr int SEG = NB / 4;             // 256 float4 per segment

    // issue all 12 loads up front
    float4 a[4], b[4], c[4];
    #pragma unroll
    for (int q = 0; q < 4; ++q) a[q] = p4[lane + q * 64];
    #pragma unroll
    for (int q = 0; q < 4; ++q) b[q] = p4[SEG + lane + q * 64];
    #pragma unroll
    for (int q = 0; q < 4; ++q) c[q] = p4[2 * SEG + lane + q * 64];

    float ce = 0.0f, tp = 0.0f, cnt = 0.0f;
    #pragma unroll
    for (int q = 0; q < 4; ++q) {
        ce  += (a[q].x + a[q].y) + (a[q].z + a[q].w);
        tp  += (b[q].x + b[q].y) + (b[q].z + b[q].w);
        cnt += (c[q].x + c[q].y) + (c[q].z + c[q].w);
    }
    ce  = wave_reduce_sum(ce);
    tp  = wave_reduce_sum(tp);
    cnt = wave_reduce_sum(cnt);
    if (lane == 0) {
        const float base_loss   = ce / (float)B;
        const float recall_loss = 1.0f - tp / (cnt + 1e-8f);
        out[0] = base_loss + 0.5f * recall_loss;
    }
}

extern "C" void kernel_launch(void* const* d_in, const int* in_sizes, int n_in,
                              void* d_out, int out_size, void* d_ws, size_t ws_size,
                              hipStream_t stream) {
    const float* logits  = (const float*)d_in[0];
    const int*   targets = (const int*)d_in[1];
    const float* counts  = (const float*)d_in[2];
    float* out  = (float*)d_out;
    float* part = (float*)d_ws;   // 3*NB floats = 12 KB scratch
    const int B = in_sizes[1];

    mrl_pass1<<<NB, NT, 0, stream>>>(logits, targets, counts, part, B);
    mrl_pass2<<<1, 64, 0, stream>>>(part, out, B);
}